// Round 9
// baseline (614.374 us; speedup 1.0000x reference)
//
#include <hip/hip_runtime.h>
#include <math.h>

// clDice loss via register-resident temporal cascade (float2 lanes).
// All 10 soft_skel iterations run as a systolic pipeline of erode stages,
// swept top->bottom. Per lane: 2 columns (float2), per stage a 3-row rolling
// register window. No LDS, no barriers; horizontal halo via DPP wave shifts.
// R6: min/max trees as single VOP3 v_min3_f32/v_max3_f32.
// R7: 6 row-strips x 960 blocks: 510us, VGPR 60, no scratch.
// R8-R10 (reverted): LDS ring / body triplication / fences -> all spilled.
//   LESSON: exactly ONE copy of the hot body, no capturing-lambda bodies.
// R11: packed fp32 epilogue (VOP3P). -13% VALU instr -> dur FLAT.
//   LESSON: not VALU-issue-bound (real util ~27-35%; VALUBusy ~2x inflated).
// R12: raw-defer loads (sigmoid/mask at consumption): 518 -> 457us.
//   Wait-at-load stall confirmed and removed.
// R13: img prefetch depth 2: FLAT (458). Load latency no longer binding.
//   Residual: each wave still stalled ~90% of wall on overlappable hazards
//   (dep chains/DPP/branch bubbles) -- or a shared per-CU resource.
// R14: supply the missing TLP. VGPR=64 permits 8 waves/SIMD but grid gave
//   3.75. 12 row-strips of 86: 10x12x64 = 7680 waves = 1920 blocks =
//   7.5 blocks/CU = 30 waves/CU. +13.8% total work (warmup/drain amortizes
//   over 86 rows), ~2x issue-fill potential. Disambiguates overlappable
//   stall (expect ~340-390us) vs shared-resource wall (expect ~500-520us).
//
// Geometry: wave covers 128 cols (lane*2 + 104*s - 12), owns 104 [104s,..).
// 10 col-strips x 12 row-strips(86 rows, 11-row warmup / 12-row drain)
// x 64 jobs (= 2 tensors x 16 batch x 2 ch) = 7680 waves = 1920 blocks.

#define HH 1024
#define WW 1024
#define OWN_W 104
#define SROWS 86    // row strip height; y0 = v*86, last strip = 78 rows
#define NMACRO 37   // 111 steps = 86 + 11 warmup + 12 drain + 2 pad

#define MOD3(x) ((((x) % 3) + 3) % 3)

typedef float v2f __attribute__((ext_vector_type(2)));

__device__ __forceinline__ float2 f2s(float v) { float2 r; r.x = v; r.y = v; return r; }
__device__ __forceinline__ float sigm(float x) { return __builtin_amdgcn_rcpf(1.0f + __expf(-x)); }

// single-instruction VOP3 3-operand min/max (no IEEE canonicalize padding)
__device__ __forceinline__ float vmin3(float a, float b, float c) {
    float d; asm("v_min3_f32 %0, %1, %2, %3" : "=v"(d) : "v"(a), "v"(b), "v"(c)); return d;
}
__device__ __forceinline__ float vmax3(float a, float b, float c) {
    float d; asm("v_max3_f32 %0, %1, %2, %3" : "=v"(d) : "v"(a), "v"(b), "v"(c)); return d;
}
__device__ __forceinline__ float vmax(float a, float b) {
    float d; asm("v_max_f32 %0, %1, %2" : "=v"(d) : "v"(a), "v"(b)); return d;
}
__device__ __forceinline__ float relu(float x) {
    float d; asm("v_max_f32 %0, 0, %1" : "=v"(d) : "v"(x)); return d;
}
__device__ __forceinline__ float min5(float a, float b, float c, float d, float e) {
    return vmin3(vmin3(a, b, c), d, e);
}

// ---- VOP3P packed fp32: one instruction, two lanes of work ----
__device__ __forceinline__ float2 pk_sub(float2 a, float2 b) {   // a - b
    v2f av = {a.x, a.y}, bv = {b.x, b.y}, dv;
    asm("v_pk_add_f32 %0, %1, %2 neg_lo:[0,1] neg_hi:[0,1]"
        : "=v"(dv) : "v"(av), "v"(bv));
    float2 r; r.x = dv.x; r.y = dv.y; return r;
}
__device__ __forceinline__ float2 pk_add(float2 a, float2 b) {   // a + b
    v2f av = {a.x, a.y}, bv = {b.x, b.y}, dv;
    asm("v_pk_add_f32 %0, %1, %2" : "=v"(dv) : "v"(av), "v"(bv));
    float2 r; r.x = dv.x; r.y = dv.y; return r;
}
__device__ __forceinline__ float2 pk_fma(float2 a, float2 b, float2 c) {  // a*b + c
    v2f av = {a.x, a.y}, bv = {b.x, b.y}, cv = {c.x, c.y}, dv;
    asm("v_pk_fma_f32 %0, %1, %2, %3" : "=v"(dv) : "v"(av), "v"(bv), "v"(cv));
    float2 r; r.x = dv.x; r.y = dv.y; return r;
}

// lane i <- lane i-1 across the full wave (== __shfl_up(x,1,64)); lane 0 keeps own.
__device__ __forceinline__ float dpp_up1(float x) {
    int i = __builtin_bit_cast(int, x);
    int r = __builtin_amdgcn_update_dpp(i, i, 0x138, 0xf, 0xf, false);  // wave_shr:1
    return __builtin_bit_cast(float, r);
}
// lane i <- lane i+1 across the full wave (== __shfl_down(x,1,64)); lane 63 keeps own.
__device__ __forceinline__ float dpp_dn1(float x) {
    int i = __builtin_bit_cast(int, x);
    int r = __builtin_amdgcn_update_dpp(i, i, 0x130, 0xf, 0xf, false);  // wave_shl:1
    return __builtin_bit_cast(float, r);
}

__global__ __launch_bounds__(256, 4)
void skel_kernel(const float* __restrict__ logits,
                 const float* __restrict__ targets,
                 float* __restrict__ sums)
{
    const int lane = threadIdx.x & 63;
    const int gwid = __builtin_amdgcn_readfirstlane(blockIdx.x * 4 + (threadIdx.x >> 6));
    const int job  = gwid / 120;         // 0..63
    const int rem  = gwid - job * 120;
    const int s    = rem % 10;           // col strip 0..9
    const int v    = rem / 10;           // row strip 0..11
    const int tensor = job >> 5;         // 0: skel(pred), 1: skel(target)
    const int plane  = job & 31;
    const size_t planeOff = (size_t)plane * (HH * WW);
    const float* __restrict__ src  = tensor ? targets : logits;   // skel source
    const float* __restrict__ osrc = tensor ? logits  : targets;  // multiplied tensor
    const bool sEdge = (s == 0) || (s == 9);

    const int colBase = OWN_W * s - 12 + lane * 2;
    const bool colOOB = (colBase < 0) || (colBase > WW - 2);      // whole-lane (even boundaries)
    const int colC = colBase < 0 ? 0 : (colBase > WW - 2 ? WW - 2 : colBase);
    const int y0  = v * SROWS;
    const int yHi = (y0 + SROWS < HH) ? (y0 + SROWS) : HH;        // runtime strip end
    const int rBase = y0 - 11;

    const int ownHi = (OWN_W * (s + 1) < WW) ? OWN_W * (s + 1) : WW;
    const bool ownedLane = (colBase >= OWN_W * s) && (colBase < ownHi);

    // E[k][slot]: stage-k erode output, 3-row rolling window. Row y lives at
    // slot (y - rBase) mod 3 (stage-independent). E[0] = source image window.
    float2 E[11][3];
#pragma unroll
    for (int k = 0; k < 11; ++k)
#pragma unroll
        for (int j = 0; j < 3; ++j) E[k][j] = f2s(INFINITY);

    // shift-register ring of 'other' rows; at macro m, slot j holds row
    // (y0 - 23 + 3m + j). Stage k, phase p reads slot 10+p-k (row = dilate row).
    float2 oring[15];
#pragma unroll
    for (int j = 0; j < 15; ++j) oring[j] = f2s(0.f);

    float2 sumS = f2s(0.f), sumP = f2s(0.f);

    // RAW loads: no VALU on the loaded value at the load site -> the
    // compiler's s_waitcnt lands at the (much later) consumption point.
    auto loadImgRaw = [&](int row) -> float2 {
        if ((unsigned)row < HH) {
            return *(const float2*)(src + planeOff + (size_t)row * WW + colC);
        }
        return f2s(INFINITY);   // out-of-image rows: erode identity (no load)
    };
    auto cookImg = [&](float2 x, int row) -> float2 {
        if ((unsigned)row < HH) {          // wave-uniform
            if (!tensor) { x.x = sigm(x.x); x.y = sigm(x.y); }
            if (sEdge && colOOB) x = f2s(INFINITY);
        }
        return x;
    };
    auto loadOtherRaw = [&](int row) -> float2 {
        int rc = row < 0 ? 0 : (row > HH - 1 ? HH - 1 : row);   // address clamp only
        return *(const float2*)(osrc + planeOff + (size_t)rc * WW + colC);
    };

    // prologue: img prefetch + macro 0's ring rows
    float2 rawImgA = loadImgRaw(rBase);       // row for step 0
    float2 rawImgB = loadImgRaw(rBase + 1);   // row for step 1
    float2 rawO[3];
#pragma unroll
    for (int j = 0; j < 3; ++j) rawO[j] = loadOtherRaw(rBase + j);

#pragma unroll 1
    for (int m = 0; m < NMACRO; ++m) {
        // ring shift
#pragma unroll
        for (int j = 0; j < 12; ++j) oring[j] = oring[j + 3];
        // cook raws issued LAST macro (rows rBase+3m+j) into slots 12-14
        // (sigmoid applied exactly once per row)
#pragma unroll
        for (int j = 0; j < 3; ++j) {
            float2 o = rawO[j];
            if (tensor) { o.x = sigm(o.x); o.y = sigm(o.y); }
            oring[12 + j] = o;
        }
        // issue NEXT macro's raw ring loads (consumed >= 3 steps from now)
#pragma unroll
        for (int j = 0; j < 3; ++j) rawO[j] = loadOtherRaw(rBase + 3 * (m + 1) + j);

#pragma unroll
        for (int p = 0; p < 3; ++p) {
            const int r = rBase + 3 * m + p;     // img row fed this step
            const float2 img = cookImg(rawImgA, r);  // waitcnt: load issued 2 steps ago
            rawImgA = rawImgB;                       // pipeline shift (renamed away)
            rawImgB = loadImgRaw(r + 2);             // issue row for step t+2

            // ---------- Pass D: dilate stage k at row yd = r-k-2 (pre-update windows) ----------
#pragma unroll
            for (int k = 1; k <= 10; ++k) {
                const int yd = r - k - 2;
                if (yd >= y0 && yd < yHi) {             // wave-uniform ownership guard
                    const float2 a = E[k][MOD3(p - k)];       // row yd-1
                    const float2 b = E[k][MOD3(p - k + 1)];   // row yd
                    const float2 c = E[k][MOD3(p - k + 2)];   // row yd+1
                    float2 vm;
                    if (yd == 0) {                // image top: exclude row -1
                        vm.x = vmax(b.x, c.x); vm.y = vmax(b.y, c.y);
                    } else if (yd == HH - 1) {    // image bottom: exclude row 1024
                        vm.x = vmax(a.x, b.x); vm.y = vmax(a.y, b.y);
                    } else {
                        vm.x = vmax3(a.x, b.x, c.x); vm.y = vmax3(a.y, b.y, c.y);
                    }
                    if (sEdge) { if (colOOB) vm = f2s(-INFINITY); }  // col truncation at image edge
                    const float vl = dpp_up1(vm.y);
                    const float vr = dpp_dn1(vm.x);
                    float2 h;
                    h.x = vmax3(vl,   vm.x, vm.y);
                    h.y = vmax3(vm.x, vm.y, vr);
                    const float2 io = E[k - 1][MOD3(p - k + 1)];  // img_k at row yd
                    // packed epilogue: ct = relu(io - h); sumS += ct; sumP += ot*ct
                    const float2 d_ = pk_sub(io, h);
                    float2 ct;
                    ct.x = relu(d_.x);
                    ct.y = relu(d_.y);
                    const float2 ot = oring[10 + p - k];
                    sumS = pk_add(sumS, ct);
                    sumP = pk_fma(ot, ct, sumP);
                }
            }

            // ---------- Pass E: erode cascade, stage k emits row r-k ----------
            E[0][MOD3(p)] = img;
            float2 np_ = img;    // new row of stage k-1 (row r-k+1 when at stage k)
#pragma unroll
            for (int k = 1; k <= 10; ++k) {
                const float2 A = E[k - 1][MOD3(p - k + 2)];  // row r-k-1 (up)
                const float2 B = E[k - 1][MOD3(p - k)];      // row r-k   (center)
                const float2 C = np_;                        // row r-k+1 (down)
                const float bl = dpp_up1(B.y);
                const float br = dpp_dn1(B.x);
                float2 ne;
                ne.x = min5(A.x, C.x, bl,  B.y, B.x);
                ne.y = min5(A.y, C.y, B.x, br,  B.y);
                const int yN = r - k;
                if ((unsigned)yN >= HH) {        // out-of-image rows stay +inf
                    ne = f2s(INFINITY);
                } else if (sEdge) {
                    if (colOOB) ne = f2s(INFINITY);  // out-of-image cols stay +inf
                }
                E[k][MOD3(p - k)] = ne;
                np_ = ne;
            }
        }
    }

    // ---------- reduce: mask unowned lanes, wave-reduce, 2 atomics ----------
    if (!ownedLane) { sumS = f2s(0.f); sumP = f2s(0.f); }
    float aS = sumS.x + sumS.y;
    float aP = sumP.x + sumP.y;
#pragma unroll
    for (int off = 32; off > 0; off >>= 1) {
        aS += __shfl_down(aS, off, 64);
        aP += __shfl_down(aP, off, 64);
    }
    if (lane == 0) {
        const int base = plane * 4 + tensor * 2;
        atomicAdd(&sums[base],     aS);   // sum(skel)
        atomicAdd(&sums[base + 1], aP);   // sum(skel * other)
    }
}

__global__ void finalize_kernel(const float* __restrict__ s4, float* __restrict__ out)
{
    __shared__ float cl[32];
    int p = threadIdx.x;
    if (p < 32) {
        const float* s = s4 + p * 4;
        float tprec = s[1] / (s[0] + 1e-6f);
        float tsens = s[3] / (s[2] + 1e-6f);
        cl[p] = 2.f * tprec * tsens / (tprec + tsens + 1e-6f);
    }
    __syncthreads();
    if (p == 0) {
        float a = 0.f, vch = 0.f;
        for (int b = 0; b < 16; ++b) { a += cl[b * 2]; vch += cl[b * 2 + 1]; }
        out[0] = 1.f - 0.5f * (a / 16.f + vch / 16.f);
    }
}

extern "C" void kernel_launch(void* const* d_in, const int* in_sizes, int n_in,
                              void* d_out, int out_size, void* d_ws, size_t ws_size,
                              hipStream_t stream)
{
    const float* logits  = (const float*)d_in[0];
    const float* targets = (const float*)d_in[1];
    float* out  = (float*)d_out;
    float* sums = (float*)d_ws;

    hipMemsetAsync(d_ws, 0, 32 * 4 * sizeof(float), stream);

    // 7680 waves = 10 col-strips x 12 row-strips x 64 jobs; 4 waves per block
    // = 1920 blocks = 7.5 blocks/CU (30 waves/CU; VGPR 64 -> 8 waves/SIMD OK).
    skel_kernel<<<1920, 256, 0, stream>>>(logits, targets, sums);
    finalize_kernel<<<1, 64, 0, stream>>>(sums, out);
}

// Round 10
// 605.190 us; speedup vs baseline: 1.0152x; 1.0152x over previous
//
#include <hip/hip_runtime.h>
#include <math.h>

// clDice loss via register-resident temporal cascade (float2 lanes).
// All 10 soft_skel iterations run as a systolic pipeline of erode stages,
// swept top->bottom. Per lane: 2 columns (float2), per stage a 3-row rolling
// register window. No LDS, no barriers; horizontal halo via DPP wave shifts.
// R6: min/max trees as single VOP3 v_min3_f32/v_max3_f32.
// R7: 6 row-strips x 960 blocks: 510us, VGPR 60, no scratch.
// R8-R10 (reverted): LDS ring / body triplication / fences -> all spilled.
//   LESSON: exactly ONE copy of the hot body, no capturing-lambda bodies.
// R11: packed fp32 epilogue (VOP3P). -13% VALU instr -> dur FLAT.
//   LESSON: not simply VALU-issue-bound at source-count level.
// R12: raw-defer loads (sigmoid/mask at consumption): 518 -> 457us. BEST.
//   Wait-at-load stall confirmed and removed.
// R13: img prefetch depth 2: FLAT (458). Load latency fully covered at depth 1.
// R14: 12 strips x 1920 blocks: 470us, occupancy 34->36.5 only.
//   LESSON: residency hard-capped ~4 blocks/CU by register file (~128 total
//   regs; "VGPR 64" = arch/accum-offset only). Extra blocks queue; +13.8%
//   warmup/drain work not recovered. TLP axis exhausted.
// R15: revert to the proven optimum: R12 geometry (6 strips, 960 blocks)
//   + depth-1 prefetch. All four axes (instr count, load latency, prefetch
//   depth, TLP) probed; this is the measured best configuration.
//
// Geometry: wave covers 128 cols (lane*2 + 104*s - 12), owns 104 [104s,..).
// 10 col-strips x 6 row-strips(171 rows, 11-row warmup / 12-row drain)
// x 64 jobs (= 2 tensors x 16 batch x 2 ch) = 3840 waves = 960 blocks.

#define HH 1024
#define WW 1024
#define OWN_W 104
#define SROWS 171   // row strip height; y0 = v*171, last strip = 169 rows
#define NMACRO 65   // 195 steps = 171 + 11 warmup + 12 drain + 1 pad

#define MOD3(x) ((((x) % 3) + 3) % 3)

typedef float v2f __attribute__((ext_vector_type(2)));

__device__ __forceinline__ float2 f2s(float v) { float2 r; r.x = v; r.y = v; return r; }
__device__ __forceinline__ float sigm(float x) { return __builtin_amdgcn_rcpf(1.0f + __expf(-x)); }

// single-instruction VOP3 3-operand min/max (no IEEE canonicalize padding)
__device__ __forceinline__ float vmin3(float a, float b, float c) {
    float d; asm("v_min3_f32 %0, %1, %2, %3" : "=v"(d) : "v"(a), "v"(b), "v"(c)); return d;
}
__device__ __forceinline__ float vmax3(float a, float b, float c) {
    float d; asm("v_max3_f32 %0, %1, %2, %3" : "=v"(d) : "v"(a), "v"(b), "v"(c)); return d;
}
__device__ __forceinline__ float vmax(float a, float b) {
    float d; asm("v_max_f32 %0, %1, %2" : "=v"(d) : "v"(a), "v"(b)); return d;
}
__device__ __forceinline__ float relu(float x) {
    float d; asm("v_max_f32 %0, 0, %1" : "=v"(d) : "v"(x)); return d;
}
__device__ __forceinline__ float min5(float a, float b, float c, float d, float e) {
    return vmin3(vmin3(a, b, c), d, e);
}

// ---- VOP3P packed fp32: one instruction, two lanes of work ----
__device__ __forceinline__ float2 pk_sub(float2 a, float2 b) {   // a - b
    v2f av = {a.x, a.y}, bv = {b.x, b.y}, dv;
    asm("v_pk_add_f32 %0, %1, %2 neg_lo:[0,1] neg_hi:[0,1]"
        : "=v"(dv) : "v"(av), "v"(bv));
    float2 r; r.x = dv.x; r.y = dv.y; return r;
}
__device__ __forceinline__ float2 pk_add(float2 a, float2 b) {   // a + b
    v2f av = {a.x, a.y}, bv = {b.x, b.y}, dv;
    asm("v_pk_add_f32 %0, %1, %2" : "=v"(dv) : "v"(av), "v"(bv));
    float2 r; r.x = dv.x; r.y = dv.y; return r;
}
__device__ __forceinline__ float2 pk_fma(float2 a, float2 b, float2 c) {  // a*b + c
    v2f av = {a.x, a.y}, bv = {b.x, b.y}, cv = {c.x, c.y}, dv;
    asm("v_pk_fma_f32 %0, %1, %2, %3" : "=v"(dv) : "v"(av), "v"(bv), "v"(cv));
    float2 r; r.x = dv.x; r.y = dv.y; return r;
}

// lane i <- lane i-1 across the full wave (== __shfl_up(x,1,64)); lane 0 keeps own.
__device__ __forceinline__ float dpp_up1(float x) {
    int i = __builtin_bit_cast(int, x);
    int r = __builtin_amdgcn_update_dpp(i, i, 0x138, 0xf, 0xf, false);  // wave_shr:1
    return __builtin_bit_cast(float, r);
}
// lane i <- lane i+1 across the full wave (== __shfl_down(x,1,64)); lane 63 keeps own.
__device__ __forceinline__ float dpp_dn1(float x) {
    int i = __builtin_bit_cast(int, x);
    int r = __builtin_amdgcn_update_dpp(i, i, 0x130, 0xf, 0xf, false);  // wave_shl:1
    return __builtin_bit_cast(float, r);
}

__global__ __launch_bounds__(256, 4)
void skel_kernel(const float* __restrict__ logits,
                 const float* __restrict__ targets,
                 float* __restrict__ sums)
{
    const int lane = threadIdx.x & 63;
    const int gwid = __builtin_amdgcn_readfirstlane(blockIdx.x * 4 + (threadIdx.x >> 6));
    const int job  = gwid / 60;          // 0..63
    const int rem  = gwid - job * 60;
    const int s    = rem % 10;           // col strip 0..9
    const int v    = rem / 10;           // row strip 0..5
    const int tensor = job >> 5;         // 0: skel(pred), 1: skel(target)
    const int plane  = job & 31;
    const size_t planeOff = (size_t)plane * (HH * WW);
    const float* __restrict__ src  = tensor ? targets : logits;   // skel source
    const float* __restrict__ osrc = tensor ? logits  : targets;  // multiplied tensor
    const bool sEdge = (s == 0) || (s == 9);

    const int colBase = OWN_W * s - 12 + lane * 2;
    const bool colOOB = (colBase < 0) || (colBase > WW - 2);      // whole-lane (even boundaries)
    const int colC = colBase < 0 ? 0 : (colBase > WW - 2 ? WW - 2 : colBase);
    const int y0  = v * SROWS;
    const int yHi = (y0 + SROWS < HH) ? (y0 + SROWS) : HH;        // runtime strip end
    const int rBase = y0 - 11;

    const int ownHi = (OWN_W * (s + 1) < WW) ? OWN_W * (s + 1) : WW;
    const bool ownedLane = (colBase >= OWN_W * s) && (colBase < ownHi);

    // E[k][slot]: stage-k erode output, 3-row rolling window. Row y lives at
    // slot (y - rBase) mod 3 (stage-independent). E[0] = source image window.
    float2 E[11][3];
#pragma unroll
    for (int k = 0; k < 11; ++k)
#pragma unroll
        for (int j = 0; j < 3; ++j) E[k][j] = f2s(INFINITY);

    // shift-register ring of 'other' rows; at macro m, slot j holds row
    // (y0 - 23 + 3m + j). Stage k, phase p reads slot 10+p-k (row = dilate row).
    float2 oring[15];
#pragma unroll
    for (int j = 0; j < 15; ++j) oring[j] = f2s(0.f);

    float2 sumS = f2s(0.f), sumP = f2s(0.f);

    // RAW loads: no VALU on the loaded value at the load site -> the
    // compiler's s_waitcnt lands at the (much later) consumption point.
    auto loadImgRaw = [&](int row) -> float2 {
        if ((unsigned)row < HH) {
            return *(const float2*)(src + planeOff + (size_t)row * WW + colC);
        }
        return f2s(INFINITY);   // out-of-image rows: erode identity (no load)
    };
    auto cookImg = [&](float2 x, int row) -> float2 {
        if ((unsigned)row < HH) {          // wave-uniform
            if (!tensor) { x.x = sigm(x.x); x.y = sigm(x.y); }
            if (sEdge && colOOB) x = f2s(INFINITY);
        }
        return x;
    };
    auto loadOtherRaw = [&](int row) -> float2 {
        int rc = row < 0 ? 0 : (row > HH - 1 ? HH - 1 : row);   // address clamp only
        return *(const float2*)(osrc + planeOff + (size_t)rc * WW + colC);
    };

    // prologue: issue raws for step 0 and for macro 0's ring rows
    float2 rawImg = loadImgRaw(rBase);
    float2 rawO[3];
#pragma unroll
    for (int j = 0; j < 3; ++j) rawO[j] = loadOtherRaw(rBase + j);

#pragma unroll 1
    for (int m = 0; m < NMACRO; ++m) {
        // ring shift
#pragma unroll
        for (int j = 0; j < 12; ++j) oring[j] = oring[j + 3];
        // cook raws issued LAST macro (rows rBase+3m+j) into slots 12-14
        // (sigmoid applied exactly once per row)
#pragma unroll
        for (int j = 0; j < 3; ++j) {
            float2 o = rawO[j];
            if (tensor) { o.x = sigm(o.x); o.y = sigm(o.y); }
            oring[12 + j] = o;
        }
        // issue NEXT macro's raw ring loads (consumed >= 3 steps from now)
#pragma unroll
        for (int j = 0; j < 3; ++j) rawO[j] = loadOtherRaw(rBase + 3 * (m + 1) + j);

#pragma unroll
        for (int p = 0; p < 3; ++p) {
            const int r = rBase + 3 * m + p;     // img row fed this step
            const float2 img = cookImg(rawImg, r);   // waitcnt lands HERE (1 step after issue)
            rawImg = loadImgRaw(r + 1);              // issue next step's raw row

            // ---------- Pass D: dilate stage k at row yd = r-k-2 (pre-update windows) ----------
#pragma unroll
            for (int k = 1; k <= 10; ++k) {
                const int yd = r - k - 2;
                if (yd >= y0 && yd < yHi) {             // wave-uniform ownership guard
                    const float2 a = E[k][MOD3(p - k)];       // row yd-1
                    const float2 b = E[k][MOD3(p - k + 1)];   // row yd
                    const float2 c = E[k][MOD3(p - k + 2)];   // row yd+1
                    float2 vm;
                    if (yd == 0) {                // image top: exclude row -1
                        vm.x = vmax(b.x, c.x); vm.y = vmax(b.y, c.y);
                    } else if (yd == HH - 1) {    // image bottom: exclude row 1024
                        vm.x = vmax(a.x, b.x); vm.y = vmax(a.y, b.y);
                    } else {
                        vm.x = vmax3(a.x, b.x, c.x); vm.y = vmax3(a.y, b.y, c.y);
                    }
                    if (sEdge) { if (colOOB) vm = f2s(-INFINITY); }  // col truncation at image edge
                    const float vl = dpp_up1(vm.y);
                    const float vr = dpp_dn1(vm.x);
                    float2 h;
                    h.x = vmax3(vl,   vm.x, vm.y);
                    h.y = vmax3(vm.x, vm.y, vr);
                    const float2 io = E[k - 1][MOD3(p - k + 1)];  // img_k at row yd
                    // packed epilogue: ct = relu(io - h); sumS += ct; sumP += ot*ct
                    const float2 d_ = pk_sub(io, h);
                    float2 ct;
                    ct.x = relu(d_.x);
                    ct.y = relu(d_.y);
                    const float2 ot = oring[10 + p - k];
                    sumS = pk_add(sumS, ct);
                    sumP = pk_fma(ot, ct, sumP);
                }
            }

            // ---------- Pass E: erode cascade, stage k emits row r-k ----------
            E[0][MOD3(p)] = img;
            float2 np_ = img;    // new row of stage k-1 (row r-k+1 when at stage k)
#pragma unroll
            for (int k = 1; k <= 10; ++k) {
                const float2 A = E[k - 1][MOD3(p - k + 2)];  // row r-k-1 (up)
                const float2 B = E[k - 1][MOD3(p - k)];      // row r-k   (center)
                const float2 C = np_;                        // row r-k+1 (down)
                const float bl = dpp_up1(B.y);
                const float br = dpp_dn1(B.x);
                float2 ne;
                ne.x = min5(A.x, C.x, bl,  B.y, B.x);
                ne.y = min5(A.y, C.y, B.x, br,  B.y);
                const int yN = r - k;
                if ((unsigned)yN >= HH) {        // out-of-image rows stay +inf
                    ne = f2s(INFINITY);
                } else if (sEdge) {
                    if (colOOB) ne = f2s(INFINITY);  // out-of-image cols stay +inf
                }
                E[k][MOD3(p - k)] = ne;
                np_ = ne;
            }
        }
    }

    // ---------- reduce: mask unowned lanes, wave-reduce, 2 atomics ----------
    if (!ownedLane) { sumS = f2s(0.f); sumP = f2s(0.f); }
    float aS = sumS.x + sumS.y;
    float aP = sumP.x + sumP.y;
#pragma unroll
    for (int off = 32; off > 0; off >>= 1) {
        aS += __shfl_down(aS, off, 64);
        aP += __shfl_down(aP, off, 64);
    }
    if (lane == 0) {
        const int base = plane * 4 + tensor * 2;
        atomicAdd(&sums[base],     aS);   // sum(skel)
        atomicAdd(&sums[base + 1], aP);   // sum(skel * other)
    }
}

__global__ void finalize_kernel(const float* __restrict__ s4, float* __restrict__ out)
{
    __shared__ float cl[32];
    int p = threadIdx.x;
    if (p < 32) {
        const float* s = s4 + p * 4;
        float tprec = s[1] / (s[0] + 1e-6f);
        float tsens = s[3] / (s[2] + 1e-6f);
        cl[p] = 2.f * tprec * tsens / (tprec + tsens + 1e-6f);
    }
    __syncthreads();
    if (p == 0) {
        float a = 0.f, vch = 0.f;
        for (int b = 0; b < 16; ++b) { a += cl[b * 2]; vch += cl[b * 2 + 1]; }
        out[0] = 1.f - 0.5f * (a / 16.f + vch / 16.f);
    }
}

extern "C" void kernel_launch(void* const* d_in, const int* in_sizes, int n_in,
                              void* d_out, int out_size, void* d_ws, size_t ws_size,
                              hipStream_t stream)
{
    const float* logits  = (const float*)d_in[0];
    const float* targets = (const float*)d_in[1];
    float* out  = (float*)d_out;
    float* sums = (float*)d_ws;

    hipMemsetAsync(d_ws, 0, 32 * 4 * sizeof(float), stream);

    // 3840 waves = 10 col-strips x 6 row-strips x 64 jobs; 4 waves per block
    // = 960 blocks <= 4 blocks/CU register cap -> fully co-resident, no queue.
    skel_kernel<<<960, 256, 0, stream>>>(logits, targets, sums);
    finalize_kernel<<<1, 64, 0, stream>>>(sums, out);
}